// Round 14
// baseline (186.702 us; speedup 1.0000x reference)
//
#include <hip/hip_runtime.h>
#include <math.h>

#define SEQ   2048
#define HID   1024
#define INTER 2048
#define DST   16
#define DTR   64
#define NP    96   // DTR + 2*DST
#define NC    64   // scan chunks
#define LCH   32   // steps per chunk (NC*LCH == SEQ)
#define KS    16   // split-K factor for h @ W_x

typedef _Float16 f16;
typedef _Float16 f16x8 __attribute__((ext_vector_type(8)));
typedef _Float16 f16x4v __attribute__((ext_vector_type(4)));
typedef _Float16 f16x2 __attribute__((ext_vector_type(2)));
typedef float f32x4 __attribute__((ext_vector_type(4)));

__device__ __forceinline__ float sigmoidf_(float x) { return 1.0f / (1.0f + expf(-x)); }
__device__ __forceinline__ float siluf_(float x)    { return x * sigmoidf_(x); }
__device__ __forceinline__ float softplusf_(float x){ return (x > 20.0f) ? x : log1pf(expf(x)); }

struct Args {
    const float* x; const float* W_in; const float* W_out; const float* W_x; const float* W_dt;
    const float* conv_w; const float* conv_b; const float* b_dt; const float* A_log; const float* Dv;
    float* out;
    f16* xh; f16* W_in_t; f16* W_out_t; f16* WxT; f16* WdtT;
    f16* projh; f16* hh; f16* dtbh; f16* yh; f16* parts;
    f16x2* SPbuf; f16* Cin;
};

// ---------------------------------------------------------------------------
// 32x32 tile transpose f32 -> f16^T through LDS scratch t[32][33]
// ---------------------------------------------------------------------------
__device__ __forceinline__ void tile_transpose(const float* __restrict__ W,
                                               f16* __restrict__ Wt,
                                               int K, int N, int bx, int by,
                                               int tid, float* t)
{
    const int n0 = bx * 32, k0 = by * 32;
    const int j = tid & 31, i0 = tid >> 5;   // i0: 0..7
#pragma unroll
    for (int r = 0; r < 4; ++r)
        t[(i0 + r * 8) * 33 + j] = W[(size_t)(k0 + i0 + r * 8) * N + n0 + j];
    __syncthreads();
#pragma unroll
    for (int r = 0; r < 4; ++r)
        Wt[(size_t)(n0 + i0 + r * 8) * K + k0 + j] = (f16)t[j * 33 + i0 + r * 8];
}

// ---------------------------------------------------------------------------
// m97-structure MFMA f16 GEMM tile: C[M,N] OutT = Ah[M,KTOT] @ Bt[N,KTOT]^T
// ---------------------------------------------------------------------------
template<int BM, int BN, int KTOT, typename OutT>
__device__ __forceinline__ void gemm_tile(const f16* __restrict__ Ah,
                                          const f16* __restrict__ Bt,
                                          OutT* __restrict__ C, int N,
                                          int bx, int by, int tid,
                                          f16* As, f16* Bs)
{
    constexpr int BK = 64;
    const int wid = tid >> 6, lane = tid & 63;
    const int wr = wid >> 1, wc = wid & 1;
    const int m0 = by * BM, n0 = bx * BN;
    const int l15 = lane & 15, lhi = lane >> 4;
    constexpr int MR = BM / 32;
    constexpr int NR = BN / 32;

    f32x4 acc[MR][NR] = {};

    for (int k0 = 0; k0 < KTOT; k0 += BK) {
        constexpr int CA = BM * BK * 2 / 1024;
#pragma unroll
        for (int c0 = 0; c0 < CA; c0 += 4) {
            int c = c0 + wid;
            int e = c * 64 + lane;
            int row = e >> 3, seg = e & 7;
            __builtin_amdgcn_global_load_lds(
                (const __attribute__((address_space(1))) unsigned int*)
                    (Ah + (size_t)(m0 + row) * KTOT + k0 + seg * 8),
                (__attribute__((address_space(3))) unsigned int*)(As + c * 512),
                16, 0, 0);
        }
        constexpr int CB = BN * BK * 2 / 1024;
#pragma unroll
        for (int c0 = 0; c0 < CB; c0 += 4) {
            int c = c0 + wid;
            int e = c * 64 + lane;
            int row = e >> 3, seg = e & 7;
            __builtin_amdgcn_global_load_lds(
                (const __attribute__((address_space(1))) unsigned int*)
                    (Bt + (size_t)(n0 + row) * KTOT + k0 + seg * 8),
                (__attribute__((address_space(3))) unsigned int*)(Bs + c * 512),
                16, 0, 0);
        }
        __syncthreads();

#pragma unroll
        for (int kk = 0; kk < BK; kk += 32) {
            f16x8 af[MR], bf[NR];
#pragma unroll
            for (int i = 0; i < MR; ++i)
                af[i] = *(const f16x8*)&As[(wr * (BM / 2) + i * 16 + l15) * BK + kk + lhi * 8];
#pragma unroll
            for (int n = 0; n < NR; ++n)
                bf[n] = *(const f16x8*)&Bs[(wc * (BN / 2) + n * 16 + l15) * BK + kk + lhi * 8];
#pragma unroll
            for (int i = 0; i < MR; ++i)
#pragma unroll
                for (int n = 0; n < NR; ++n)
                    acc[i][n] = __builtin_amdgcn_mfma_f32_16x16x32_f16(af[i], bf[n], acc[i][n], 0, 0, 0);
        }
        __syncthreads();
    }

    // C/D map: col = lane&15, row = (lane>>4)*4 + reg
#pragma unroll
    for (int i = 0; i < MR; ++i)
#pragma unroll
        for (int n = 0; n < NR; ++n)
#pragma unroll
            for (int r = 0; r < 4; ++r)
                C[(size_t)(m0 + wr * (BM / 2) + i * 16 + lhi * 4 + r) * N
                  + n0 + wc * (BN / 2) + n * 16 + l15] = (OutT)acc[i][n][r];
}

// ---------------------------------------------------------------------------
// L1: x->f16 + all 4 weight transposes (8512 blocks)
// ---------------------------------------------------------------------------
__global__ __launch_bounds__(256) void k_prep(Args a)
{
    __shared__ float t[32 * 33];
    const int v = blockIdx.x, tid = threadIdx.x;
    if (v < 2048) {
        int i = (v * 256 + tid) * 4;
        float4 w = *(const float4*)&a.x[i];
        f16x4v o;
        o.x = (f16)w.x; o.y = (f16)w.y; o.z = (f16)w.z; o.w = (f16)w.w;
        *(f16x4v*)&a.xh[i] = o;
    } else if (v < 6144) {
        int q = v - 2048;                       // W_in: K=1024, N=4096
        tile_transpose(a.W_in, a.W_in_t, HID, 4096, q & 127, q >> 7, tid, t);
    } else if (v < 8192) {
        int q = v - 6144;                       // W_out: K=2048, N=1024
        tile_transpose(a.W_out, a.W_out_t, INTER, HID, q & 31, q >> 5, tid, t);
    } else if (v < 8384) {
        int q = v - 8192;                       // W_x: K=2048, N=96
        tile_transpose(a.W_x, a.WxT, INTER, NP, q % 3, q / 3, tid, t);
    } else {
        int q = v - 8384;                       // W_dt: K=64, N=2048
        tile_transpose(a.W_dt, a.WdtT, DTR, INTER, q & 63, q >> 6, tid, t);
    }
}

// ---------------------------------------------------------------------------
// L2: proj = x @ W_in (512 blocks)
// ---------------------------------------------------------------------------
__global__ __launch_bounds__(256) void k_gemm1(Args a)
{
    __shared__ __align__(16) f16 As[128 * 64];
    __shared__ __align__(16) f16 Bs[128 * 64];
    gemm_tile<128, 128, HID, f16>(a.xh, a.W_in_t, a.projh, 4096,
                                  (int)blockIdx.x % 32, (int)blockIdx.x / 32,
                                  threadIdx.x, As, Bs);
}

// ---------------------------------------------------------------------------
// L3: fused conv+silu into hwx A-staging; writes hh as byproduct. (256 blocks)
// ---------------------------------------------------------------------------
__global__ __launch_bounds__(256) void k_hwxc(Args a)
{
    constexpr int BM = 128, BN = 96, BK = 64;
    __shared__ __align__(16) f16 As[BM * BK];
    __shared__ __align__(16) f16 Bs[BN * BK];

    const int v = blockIdx.x;
    const int bxm = v & 15, ks = v >> 4;
    const int tid = threadIdx.x;
    const int wid = tid >> 6, lane = tid & 63;
    const int wr = wid >> 1, wc = wid & 1;
    const int m0 = bxm * BM;
    const int l15 = lane & 15, lhi = lane >> 4;

    f32x4 acc[4][3] = {};

    for (int k0 = ks * 128; k0 < ks * 128 + 128; k0 += BK) {
#pragma unroll
        for (int c0 = 0; c0 < 12; c0 += 4) {
            int c = c0 + wid;
            int e = c * 64 + lane;
            int row = e >> 3, seg = e & 7;
            __builtin_amdgcn_global_load_lds(
                (const __attribute__((address_space(1))) unsigned int*)
                    (a.WxT + (size_t)row * INTER + k0 + seg * 8),
                (__attribute__((address_space(3))) unsigned int*)(Bs + c * 512),
                16, 0, 0);
        }
        // A staging: conv+silu in registers -> LDS + hh byproduct
#pragma unroll
        for (int i = 0; i < 4; ++i) {
            int u = tid + i * 256;
            int row = u >> 3, seg = u & 7;
            int s = m0 + row;
            int c8 = k0 + seg * 8;
            float av[8];
#pragma unroll
            for (int j = 0; j < 8; ++j) av[j] = a.conv_b[c8 + j];
#pragma unroll
            for (int k = 0; k < 4; ++k) {
                int sp = s + k - 3;
                if (sp >= 0) {
                    f16x8 p = *(const f16x8*)&a.projh[(size_t)sp * 4096 + c8];
#pragma unroll
                    for (int j = 0; j < 8; ++j)
                        av[j] = fmaf((float)p[j], a.conv_w[k * INTER + c8 + j], av[j]);
                }
            }
            f16x8 o;
#pragma unroll
            for (int j = 0; j < 8; ++j) o[j] = (f16)siluf_(av[j]);
            *(f16x8*)&As[row * 64 + seg * 8] = o;
            *(f16x8*)&a.hh[(size_t)s * INTER + c8] = o;
        }
        __syncthreads();

#pragma unroll
        for (int kk = 0; kk < BK; kk += 32) {
            f16x8 af[4], bf[3];
#pragma unroll
            for (int i = 0; i < 4; ++i)
                af[i] = *(const f16x8*)&As[(wr * 64 + i * 16 + l15) * BK + kk + lhi * 8];
#pragma unroll
            for (int n = 0; n < 3; ++n)
                bf[n] = *(const f16x8*)&Bs[(wc * 48 + n * 16 + l15) * BK + kk + lhi * 8];
#pragma unroll
            for (int i = 0; i < 4; ++i)
#pragma unroll
                for (int n = 0; n < 3; ++n)
                    acc[i][n] = __builtin_amdgcn_mfma_f32_16x16x32_f16(af[i], bf[n], acc[i][n], 0, 0, 0);
        }
        __syncthreads();
    }

    f16* P = a.parts + (size_t)ks * (SEQ * NP);
#pragma unroll
    for (int i = 0; i < 4; ++i)
#pragma unroll
        for (int n = 0; n < 3; ++n)
#pragma unroll
            for (int r = 0; r < 4; ++r)
                P[(size_t)(m0 + wr * 64 + i * 16 + lhi * 4 + r) * NP
                  + wc * 48 + n * 16 + l15] = (f16)acc[i][n][r];
}

// ---------------------------------------------------------------------------
// L4: dt = softplus(ts @ W_dt + b_dt); ts-reduction fused into A-staging.
// (256 blocks)
// ---------------------------------------------------------------------------
__global__ __launch_bounds__(256) void k_dt(Args a)
{
    constexpr int BK = 64;
    __shared__ __align__(16) f16 As[128 * 64];
    __shared__ __align__(16) f16 Bs[128 * 64];
    const int v = blockIdx.x, tid = threadIdx.x;
    const int bx = v & 15, by = v >> 4;
    const int wid = tid >> 6, lane = tid & 63;
    const int wr = wid >> 1, wc = wid & 1;
    const int m0 = by * 128, n0 = bx * 128;
    const int l15 = lane & 15, lhi = lane >> 4;
    f32x4 acc[4][4] = {};

    // B staging (WdtT) via global_load_lds
#pragma unroll
    for (int c0 = 0; c0 < 16; c0 += 4) {
        int c = c0 + wid;
        int e = c * 64 + lane;
        int row = e >> 3, seg = e & 7;
        __builtin_amdgcn_global_load_lds(
            (const __attribute__((address_space(1))) unsigned int*)
                (a.WdtT + (size_t)(n0 + row) * DTR + seg * 8),
            (__attribute__((address_space(3))) unsigned int*)(Bs + c * 512),
            16, 0, 0);
    }
    // A staging: reduce 16 f16 partial planes (ts cols) in registers -> LDS
#pragma unroll
    for (int i = 0; i < 4; ++i) {
        int u = tid + i * 256;
        int row = u >> 3, j8 = (u & 7) * 8;
        int s = m0 + row;
        float sum[8] = {};
#pragma unroll
        for (int c = 0; c < KS; ++c) {
            f16x8 w = *(const f16x8*)&a.parts[(size_t)c * (SEQ * NP) + (size_t)s * NP + j8];
#pragma unroll
            for (int j = 0; j < 8; ++j) sum[j] += (float)w[j];
        }
        f16x8 o;
#pragma unroll
        for (int j = 0; j < 8; ++j) o[j] = (f16)sum[j];
        *(f16x8*)&As[row * 64 + j8] = o;
    }
    __syncthreads();

#pragma unroll
    for (int kk = 0; kk < 64; kk += 32) {
        f16x8 af[4], bf[4];
#pragma unroll
        for (int i = 0; i < 4; ++i)
            af[i] = *(const f16x8*)&As[(wr * 64 + i * 16 + l15) * BK + kk + lhi * 8];
#pragma unroll
        for (int n = 0; n < 4; ++n)
            bf[n] = *(const f16x8*)&Bs[(wc * 64 + n * 16 + l15) * BK + kk + lhi * 8];
#pragma unroll
        for (int i = 0; i < 4; ++i)
#pragma unroll
            for (int n = 0; n < 4; ++n)
                acc[i][n] = __builtin_amdgcn_mfma_f32_16x16x32_f16(af[i], bf[n], acc[i][n], 0, 0, 0);
    }

#pragma unroll
    for (int i = 0; i < 4; ++i)
#pragma unroll
        for (int n = 0; n < 4; ++n) {
            int col = n0 + wc * 64 + n * 16 + l15;
            float bv = a.b_dt[col];
#pragma unroll
            for (int r = 0; r < 4; ++r)
                a.dtbh[(size_t)(m0 + wr * 64 + i * 16 + lhi * 4 + r) * INTER + col] =
                    (f16)softplusf_(acc[i][n][r] + bv);
        }
}

// ---------------------------------------------------------------------------
// L5: scan pass1 -> interleaved {S,P} f16x2; B reduced from parts. (512 blocks)
// ---------------------------------------------------------------------------
__global__ __launch_bounds__(256) void k_pass1(Args a)
{
    __shared__ float Bsc[LCH * DST];
    const int v = blockIdx.x, tid = threadIdx.x;
    const int hblk = v >> 6, c = v & 63;
    const int h = hblk * 256 + tid;
    const int s0 = c * LCH;
    for (int j = tid; j < LCH * DST; j += 256) {
        int r = j >> 4, dd = j & 15;
        size_t off = (size_t)(s0 + r) * NP + DTR + dd;
        float sum = 0.0f;
#pragma unroll
        for (int cc = 0; cc < KS; ++cc)
            sum += (float)a.parts[(size_t)cc * (SEQ * NP) + off];
        Bsc[r * DST + dd] = sum;
    }
    __syncthreads();

    float A[DST], st[DST];
#pragma unroll
    for (int d = 0; d < DST; ++d) {
        A[d] = -__expf(a.A_log[(size_t)h * DST + d]);
        st[d] = 0.0f;
    }
    float dtsum = 0.0f;
#pragma unroll 2
    for (int r = 0; r < LCH; ++r) {
        float dtv = (float)a.dtbh[(size_t)(s0 + r) * INTER + h];
        float hv  = (float)a.hh[(size_t)(s0 + r) * INTER + h];
        float dh = dtv * hv;
        dtsum += dtv;
#pragma unroll
        for (int d = 0; d < DST; ++d) {
            float da = __expf(dtv * A[d]);
            st[d] = fmaf(da, st[d], dh * Bsc[r * DST + d]);
        }
    }
    size_t base = ((size_t)c * INTER + h) * DST;
#pragma unroll
    for (int d = 0; d < DST; ++d) {
        f16x2 sp;
        sp.x = (f16)st[d];
        sp.y = (f16)__expf(A[d] * dtsum);
        a.SPbuf[base + d] = sp;
    }
}

// ---------------------------------------------------------------------------
// L6: scan pass2 over chunk aggregates (128 blocks)
// ---------------------------------------------------------------------------
__global__ __launch_bounds__(256) void k_pass2(Args a)
{
    int i = blockIdx.x * 256 + threadIdx.x;   // over INTER*DST = 32768
    float carry = 0.0f;
#pragma unroll 8
    for (int c = 0; c < NC; ++c) {
        size_t idx = (size_t)c * (INTER * DST) + i;
        f16x2 sp = a.SPbuf[idx];
        a.Cin[idx] = (f16)carry;
        carry = fmaf((float)sp.y, carry, (float)sp.x);
    }
}

// ---------------------------------------------------------------------------
// L7: scan pass3 + fused epilogue -> yh; B,C reduced from parts. (512 blocks)
// ---------------------------------------------------------------------------
__global__ __launch_bounds__(256) void k_pass3(Args a)
{
    __shared__ float Bsc[LCH * DST];
    __shared__ float Csc[LCH * DST];
    const int v = blockIdx.x, tid = threadIdx.x;
    const int hblk = v >> 6, c = v & 63;
    const int h = hblk * 256 + tid;
    const int s0 = c * LCH;
    for (int j = tid; j < LCH * DST; j += 256) {
        int r = j >> 4, dd = j & 15;
        size_t offB = (size_t)(s0 + r) * NP + DTR + dd;
        float sb = 0.0f, sc = 0.0f;
#pragma unroll
        for (int cc = 0; cc < KS; ++cc) {
            sb += (float)a.parts[(size_t)cc * (SEQ * NP) + offB];
            sc += (float)a.parts[(size_t)cc * (SEQ * NP) + offB + DST];
        }
        Bsc[r * DST + dd] = sb;
        Csc[r * DST + dd] = sc;
    }
    __syncthreads();

    float A[DST], st[DST];
    size_t base = ((size_t)c * INTER + h) * DST;
#pragma unroll
    for (int d = 0; d < DST; ++d) {
        A[d] = -__expf(a.A_log[(size_t)h * DST + d]);
        st[d] = (float)a.Cin[base + d];
    }
    const float Dvv = a.Dv[h];

#pragma unroll 2
    for (int r = 0; r < LCH; ++r) {
        float dtv = (float)a.dtbh[(size_t)(s0 + r) * INTER + h];
        float hv  = (float)a.hh[(size_t)(s0 + r) * INTER + h];
        float g   = (float)a.projh[(size_t)(s0 + r) * 4096 + INTER + h];
        float dh = dtv * hv;
        float y = 0.0f;
#pragma unroll
        for (int d = 0; d < DST; ++d) {
            float da = __expf(dtv * A[d]);
            st[d] = fmaf(da, st[d], dh * Bsc[r * DST + d]);
            y = fmaf(st[d], Csc[r * DST + d], y);
        }
        y = fmaf(hv, Dvv, y);
        a.yh[(size_t)(s0 + r) * INTER + h] = (f16)(y * siluf_(g));
    }
}

// ---------------------------------------------------------------------------
// L8: out = y @ W_out (256 blocks)
// ---------------------------------------------------------------------------
__global__ __launch_bounds__(256) void k_gemm2(Args a)
{
    __shared__ __align__(16) f16 As[64 * 64];
    __shared__ __align__(16) f16 Bs[128 * 64];
    gemm_tile<64, 128, INTER, float>(a.yh, a.W_out_t, a.out, HID,
                                     (int)blockIdx.x & 7, (int)blockIdx.x >> 3,
                                     threadIdx.x, As, Bs);
}

// ---------------------------------------------------------------------------
extern "C" void kernel_launch(void* const* d_in, const int* in_sizes, int n_in,
                              void* d_out, int out_size, void* d_ws, size_t ws_size,
                              hipStream_t stream)
{
    float* ws = (float*)d_ws;
    Args a;
    a.x      = (const float*)d_in[0];
    a.W_in   = (const float*)d_in[1];
    a.conv_w = (const float*)d_in[2];
    a.conv_b = (const float*)d_in[3];
    a.W_x    = (const float*)d_in[4];
    a.W_dt   = (const float*)d_in[5];
    a.b_dt   = (const float*)d_in[6];
    a.A_log  = (const float*)d_in[7];
    a.Dv     = (const float*)d_in[8];
    a.W_out  = (const float*)d_in[9];
    a.out    = (float*)d_out;

    a.projh  = (f16*)ws;                     // SEQ x 4096 halves
    a.hh     = (f16*)(ws + 4194304);         // SEQ x INTER
    a.dtbh   = (f16*)(ws + 6291456);         // SEQ x INTER
    a.yh     = (f16*)(ws + 8388608);         // SEQ x INTER
    a.xh     = (f16*)(ws + 10485760);        // SEQ x HID
    a.W_in_t = (f16*)(ws + 11534336);        // 4096 x HID
    a.W_out_t= (f16*)(ws + 13631488);        // HID x INTER
    a.WxT    = (f16*)(ws + 14680064);        // 96 x INTER
    a.WdtT   = (f16*)(ws + 14778368);        // INTER x DTR
    a.parts  = (f16*)(ws + 14843904);        // KS x SEQ x NP halves
    a.SPbuf  = (f16x2*)(ws + 16416768);      // NC x INTER x DST f16x2
    a.Cin    = (f16*)(ws + 18513920);        // NC x INTER x DST f16

    k_prep  <<<8512, 256, 0, stream>>>(a);
    k_gemm1 <<<512,  256, 0, stream>>>(a);
    k_hwxc  <<<256,  256, 0, stream>>>(a);
    k_dt    <<<256,  256, 0, stream>>>(a);
    k_pass1 <<<512,  256, 0, stream>>>(a);
    k_pass2 <<<128,  256, 0, stream>>>(a);
    k_pass3 <<<512,  256, 0, stream>>>(a);
    k_gemm2 <<<256,  256, 0, stream>>>(a);
}

// Round 15
// 180.210 us; speedup vs baseline: 1.0360x; 1.0360x over previous
//
#include <hip/hip_runtime.h>
#include <math.h>

#define SEQ   2048
#define HID   1024
#define INTER 2048
#define DST   16
#define DTR   64
#define NP    96   // DTR + 2*DST
#define NC    64   // scan chunks
#define LCH   32   // steps per chunk (NC*LCH == SEQ)
#define KS    16   // split-K factor for h @ W_x

typedef _Float16 f16;
typedef _Float16 f16x8 __attribute__((ext_vector_type(8)));
typedef _Float16 f16x4v __attribute__((ext_vector_type(4)));
typedef _Float16 f16x2 __attribute__((ext_vector_type(2)));
typedef float f32x4 __attribute__((ext_vector_type(4)));

__device__ __forceinline__ float sigmoidf_(float x) { return 1.0f / (1.0f + expf(-x)); }
__device__ __forceinline__ float siluf_(float x)    { return x * sigmoidf_(x); }
__device__ __forceinline__ float softplusf_(float x){ return (x > 20.0f) ? x : log1pf(expf(x)); }

struct Args {
    const float* x; const float* W_in; const float* W_out; const float* W_x; const float* W_dt;
    const float* conv_w; const float* conv_b; const float* b_dt; const float* A_log; const float* Dv;
    float* out;
    f16* xh; f16* W_in_t; f16* W_out_t; f16* WxT; f16* WdtT;
    f16* projh; f16* hh; f16* dtbh; f16* yh; f16* tsh; f16* parts;
    float* ssm_p; f16x2* SPbuf; f16* Cin;
};

// ---------------------------------------------------------------------------
// 32x32 tile transpose f32 -> f16^T through LDS scratch t[32][33]
// ---------------------------------------------------------------------------
__device__ __forceinline__ void tile_transpose(const float* __restrict__ W,
                                               f16* __restrict__ Wt,
                                               int K, int N, int bx, int by,
                                               int tid, float* t)
{
    const int n0 = bx * 32, k0 = by * 32;
    const int j = tid & 31, i0 = tid >> 5;   // i0: 0..7
#pragma unroll
    for (int r = 0; r < 4; ++r)
        t[(i0 + r * 8) * 33 + j] = W[(size_t)(k0 + i0 + r * 8) * N + n0 + j];
    __syncthreads();
#pragma unroll
    for (int r = 0; r < 4; ++r)
        Wt[(size_t)(n0 + i0 + r * 8) * K + k0 + j] = (f16)t[j * 33 + i0 + r * 8];
}

// ---------------------------------------------------------------------------
// m97-structure MFMA f16 GEMM tile: C[M,N] OutT = Ah[M,KTOT] @ Bt[N,KTOT]^T
// ---------------------------------------------------------------------------
template<int BM, int BN, int KTOT, typename OutT>
__device__ __forceinline__ void gemm_tile(const f16* __restrict__ Ah,
                                          const f16* __restrict__ Bt,
                                          OutT* __restrict__ C, int N,
                                          int bx, int by, int tid,
                                          f16* As, f16* Bs)
{
    constexpr int BK = 64;
    const int wid = tid >> 6, lane = tid & 63;
    const int wr = wid >> 1, wc = wid & 1;
    const int m0 = by * BM, n0 = bx * BN;
    const int l15 = lane & 15, lhi = lane >> 4;
    constexpr int MR = BM / 32;
    constexpr int NR = BN / 32;

    f32x4 acc[MR][NR] = {};

    for (int k0 = 0; k0 < KTOT; k0 += BK) {
        constexpr int CA = BM * BK * 2 / 1024;
#pragma unroll
        for (int c0 = 0; c0 < CA; c0 += 4) {
            int c = c0 + wid;
            int e = c * 64 + lane;
            int row = e >> 3, seg = e & 7;
            __builtin_amdgcn_global_load_lds(
                (const __attribute__((address_space(1))) unsigned int*)
                    (Ah + (size_t)(m0 + row) * KTOT + k0 + seg * 8),
                (__attribute__((address_space(3))) unsigned int*)(As + c * 512),
                16, 0, 0);
        }
        constexpr int CB = BN * BK * 2 / 1024;
#pragma unroll
        for (int c0 = 0; c0 < CB; c0 += 4) {
            int c = c0 + wid;
            int e = c * 64 + lane;
            int row = e >> 3, seg = e & 7;
            __builtin_amdgcn_global_load_lds(
                (const __attribute__((address_space(1))) unsigned int*)
                    (Bt + (size_t)(n0 + row) * KTOT + k0 + seg * 8),
                (__attribute__((address_space(3))) unsigned int*)(Bs + c * 512),
                16, 0, 0);
        }
        __syncthreads();

#pragma unroll
        for (int kk = 0; kk < BK; kk += 32) {
            f16x8 af[MR], bf[NR];
#pragma unroll
            for (int i = 0; i < MR; ++i)
                af[i] = *(const f16x8*)&As[(wr * (BM / 2) + i * 16 + l15) * BK + kk + lhi * 8];
#pragma unroll
            for (int n = 0; n < NR; ++n)
                bf[n] = *(const f16x8*)&Bs[(wc * (BN / 2) + n * 16 + l15) * BK + kk + lhi * 8];
#pragma unroll
            for (int i = 0; i < MR; ++i)
#pragma unroll
                for (int n = 0; n < NR; ++n)
                    acc[i][n] = __builtin_amdgcn_mfma_f32_16x16x32_f16(af[i], bf[n], acc[i][n], 0, 0, 0);
        }
        __syncthreads();
    }

    // C/D map: col = lane&15, row = (lane>>4)*4 + reg
#pragma unroll
    for (int i = 0; i < MR; ++i)
#pragma unroll
        for (int n = 0; n < NR; ++n)
#pragma unroll
            for (int r = 0; r < 4; ++r)
                C[(size_t)(m0 + wr * (BM / 2) + i * 16 + lhi * 4 + r) * N
                  + n0 + wc * (BN / 2) + n * 16 + l15] = (OutT)acc[i][n][r];
}

// ---------------------------------------------------------------------------
// L1: x->f16 + all 4 weight transposes (8512 blocks)
// ---------------------------------------------------------------------------
__global__ __launch_bounds__(256) void k_prep(Args a)
{
    __shared__ float t[32 * 33];
    const int v = blockIdx.x, tid = threadIdx.x;
    if (v < 2048) {
        int i = (v * 256 + tid) * 4;
        float4 w = *(const float4*)&a.x[i];
        f16x4v o;
        o.x = (f16)w.x; o.y = (f16)w.y; o.z = (f16)w.z; o.w = (f16)w.w;
        *(f16x4v*)&a.xh[i] = o;
    } else if (v < 6144) {
        int q = v - 2048;                       // W_in: K=1024, N=4096
        tile_transpose(a.W_in, a.W_in_t, HID, 4096, q & 127, q >> 7, tid, t);
    } else if (v < 8192) {
        int q = v - 6144;                       // W_out: K=2048, N=1024
        tile_transpose(a.W_out, a.W_out_t, INTER, HID, q & 31, q >> 5, tid, t);
    } else if (v < 8384) {
        int q = v - 8192;                       // W_x: K=2048, N=96
        tile_transpose(a.W_x, a.WxT, INTER, NP, q % 3, q / 3, tid, t);
    } else {
        int q = v - 8384;                       // W_dt: K=64, N=2048
        tile_transpose(a.W_dt, a.WdtT, DTR, INTER, q & 63, q >> 6, tid, t);
    }
}

// ---------------------------------------------------------------------------
// L2: proj = x @ W_in (512 blocks)
// ---------------------------------------------------------------------------
__global__ __launch_bounds__(256) void k_gemm1(Args a)
{
    __shared__ __align__(16) f16 As[128 * 64];
    __shared__ __align__(16) f16 Bs[128 * 64];
    gemm_tile<128, 128, HID, f16>(a.xh, a.W_in_t, a.projh, 4096,
                                  (int)blockIdx.x % 32, (int)blockIdx.x / 32,
                                  threadIdx.x, As, Bs);
}

// ---------------------------------------------------------------------------
// L3: fused conv+silu into hwx A-staging; writes hh as byproduct. (256 blocks)
// ---------------------------------------------------------------------------
__global__ __launch_bounds__(256) void k_hwxc(Args a)
{
    constexpr int BM = 128, BN = 96, BK = 64;
    __shared__ __align__(16) f16 As[BM * BK];
    __shared__ __align__(16) f16 Bs[BN * BK];

    const int v = blockIdx.x;
    const int bxm = v & 15, ks = v >> 4;
    const int tid = threadIdx.x;
    const int wid = tid >> 6, lane = tid & 63;
    const int wr = wid >> 1, wc = wid & 1;
    const int m0 = bxm * BM;
    const int l15 = lane & 15, lhi = lane >> 4;

    f32x4 acc[4][3] = {};

    for (int k0 = ks * 128; k0 < ks * 128 + 128; k0 += BK) {
#pragma unroll
        for (int c0 = 0; c0 < 12; c0 += 4) {
            int c = c0 + wid;
            int e = c * 64 + lane;
            int row = e >> 3, seg = e & 7;
            __builtin_amdgcn_global_load_lds(
                (const __attribute__((address_space(1))) unsigned int*)
                    (a.WxT + (size_t)row * INTER + k0 + seg * 8),
                (__attribute__((address_space(3))) unsigned int*)(Bs + c * 512),
                16, 0, 0);
        }
        // A staging: conv+silu in registers -> LDS + hh byproduct
#pragma unroll
        for (int i = 0; i < 4; ++i) {
            int u = tid + i * 256;
            int row = u >> 3, seg = u & 7;
            int s = m0 + row;
            int c8 = k0 + seg * 8;
            float av[8];
#pragma unroll
            for (int j = 0; j < 8; ++j) av[j] = a.conv_b[c8 + j];
#pragma unroll
            for (int k = 0; k < 4; ++k) {
                int sp = s + k - 3;
                if (sp >= 0) {
                    f16x8 p = *(const f16x8*)&a.projh[(size_t)sp * 4096 + c8];
#pragma unroll
                    for (int j = 0; j < 8; ++j)
                        av[j] = fmaf((float)p[j], a.conv_w[k * INTER + c8 + j], av[j]);
                }
            }
            f16x8 o;
#pragma unroll
            for (int j = 0; j < 8; ++j) o[j] = (f16)siluf_(av[j]);
            *(f16x8*)&As[row * 64 + seg * 8] = o;
            *(f16x8*)&a.hh[(size_t)s * INTER + c8] = o;
        }
        __syncthreads();

#pragma unroll
        for (int kk = 0; kk < BK; kk += 32) {
            f16x8 af[4], bf[3];
#pragma unroll
            for (int i = 0; i < 4; ++i)
                af[i] = *(const f16x8*)&As[(wr * 64 + i * 16 + l15) * BK + kk + lhi * 8];
#pragma unroll
            for (int n = 0; n < 3; ++n)
                bf[n] = *(const f16x8*)&Bs[(wc * 48 + n * 16 + l15) * BK + kk + lhi * 8];
#pragma unroll
            for (int i = 0; i < 4; ++i)
#pragma unroll
                for (int n = 0; n < 3; ++n)
                    acc[i][n] = __builtin_amdgcn_mfma_f32_16x16x32_f16(af[i], bf[n], acc[i][n], 0, 0, 0);
        }
        __syncthreads();
    }

    f16* P = a.parts + (size_t)ks * (SEQ * NP);
#pragma unroll
    for (int i = 0; i < 4; ++i)
#pragma unroll
        for (int n = 0; n < 3; ++n)
#pragma unroll
            for (int r = 0; r < 4; ++r)
                P[(size_t)(m0 + wr * 64 + i * 16 + lhi * 4 + r) * NP
                  + wc * 48 + n * 16 + l15] = (f16)acc[i][n][r];
}

// ---------------------------------------------------------------------------
// L4: reduce 16 f16 planes -> ssm_p (B,C f32) + tsh (ts f16) (96 blocks)
// ---------------------------------------------------------------------------
__global__ __launch_bounds__(256) void k_reduce(Args a)
{
    int i8 = (blockIdx.x * 256 + threadIdx.x) * 8;
    int s = i8 / NP, j0 = i8 % NP;
    float acc[8] = {};
#pragma unroll
    for (int c = 0; c < KS; ++c) {
        f16x8 w = *(const f16x8*)&a.parts[(size_t)c * (SEQ * NP) + i8];
#pragma unroll
        for (int j = 0; j < 8; ++j) acc[j] += (float)w[j];
    }
    if (j0 < DTR) {
        f16x8 o;
#pragma unroll
        for (int j = 0; j < 8; ++j) o[j] = (f16)acc[j];
        *(f16x8*)&a.tsh[(size_t)s * DTR + j0] = o;
    } else {
        *(float4*)&a.ssm_p[(size_t)s * NP + j0]     = make_float4(acc[0], acc[1], acc[2], acc[3]);
        *(float4*)&a.ssm_p[(size_t)s * NP + j0 + 4] = make_float4(acc[4], acc[5], acc[6], acc[7]);
    }
}

// ---------------------------------------------------------------------------
// L5: dt = softplus(ts @ W_dt + b_dt) -> f16 (256 blocks)
// ---------------------------------------------------------------------------
__global__ __launch_bounds__(256) void k_dt(Args a)
{
    constexpr int BK = 64;
    __shared__ __align__(16) f16 As[128 * 64];
    __shared__ __align__(16) f16 Bs[128 * 64];
    const int v = blockIdx.x, tid = threadIdx.x;
    const int bx = v & 15, by = v >> 4;
    const int wid = tid >> 6, lane = tid & 63;
    const int wr = wid >> 1, wc = wid & 1;
    const int m0 = by * 128, n0 = bx * 128;
    const int l15 = lane & 15, lhi = lane >> 4;
    f32x4 acc[4][4] = {};

#pragma unroll
    for (int c0 = 0; c0 < 16; c0 += 4) {
        int c = c0 + wid;
        int e = c * 64 + lane;
        int row = e >> 3, seg = e & 7;
        __builtin_amdgcn_global_load_lds(
            (const __attribute__((address_space(1))) unsigned int*)
                (a.tsh + (size_t)(m0 + row) * DTR + seg * 8),
            (__attribute__((address_space(3))) unsigned int*)(As + c * 512),
            16, 0, 0);
        __builtin_amdgcn_global_load_lds(
            (const __attribute__((address_space(1))) unsigned int*)
                (a.WdtT + (size_t)(n0 + row) * DTR + seg * 8),
            (__attribute__((address_space(3))) unsigned int*)(Bs + c * 512),
            16, 0, 0);
    }
    __syncthreads();

#pragma unroll
    for (int kk = 0; kk < 64; kk += 32) {
        f16x8 af[4], bf[4];
#pragma unroll
        for (int i = 0; i < 4; ++i)
            af[i] = *(const f16x8*)&As[(wr * 64 + i * 16 + l15) * BK + kk + lhi * 8];
#pragma unroll
        for (int n = 0; n < 4; ++n)
            bf[n] = *(const f16x8*)&Bs[(wc * 64 + n * 16 + l15) * BK + kk + lhi * 8];
#pragma unroll
        for (int i = 0; i < 4; ++i)
#pragma unroll
            for (int n = 0; n < 4; ++n)
                acc[i][n] = __builtin_amdgcn_mfma_f32_16x16x32_f16(af[i], bf[n], acc[i][n], 0, 0, 0);
    }

#pragma unroll
    for (int i = 0; i < 4; ++i)
#pragma unroll
        for (int n = 0; n < 4; ++n) {
            int col = n0 + wc * 64 + n * 16 + l15;
            float bv = a.b_dt[col];
#pragma unroll
            for (int r = 0; r < 4; ++r)
                a.dtbh[(size_t)(m0 + wr * 64 + i * 16 + lhi * 4 + r) * INTER + col] =
                    (f16)softplusf_(acc[i][n][r] + bv);
        }
}

// ---------------------------------------------------------------------------
// L6: scan pass1 -> interleaved {S,P} f16x2 (512 blocks)
// ---------------------------------------------------------------------------
__global__ __launch_bounds__(256) void k_pass1(Args a)
{
    __shared__ float Bsc[LCH * DST];
    const int v = blockIdx.x, tid = threadIdx.x;
    const int hblk = v >> 6, c = v & 63;
    const int h = hblk * 256 + tid;
    const int s0 = c * LCH;
    for (int j = tid; j < LCH * DST; j += 256) {
        int r = j >> 4, dd = j & 15;
        Bsc[r * DST + dd] = a.ssm_p[(size_t)(s0 + r) * NP + DTR + dd];
    }
    __syncthreads();

    float A[DST], st[DST];
#pragma unroll
    for (int d = 0; d < DST; ++d) {
        A[d] = -__expf(a.A_log[(size_t)h * DST + d]);
        st[d] = 0.0f;
    }
    float dtsum = 0.0f;
#pragma unroll 2
    for (int r = 0; r < LCH; ++r) {
        float dtv = (float)a.dtbh[(size_t)(s0 + r) * INTER + h];
        float hv  = (float)a.hh[(size_t)(s0 + r) * INTER + h];
        float dh = dtv * hv;
        dtsum += dtv;
#pragma unroll
        for (int d = 0; d < DST; ++d) {
            float da = __expf(dtv * A[d]);
            st[d] = fmaf(da, st[d], dh * Bsc[r * DST + d]);
        }
    }
    size_t base = ((size_t)c * INTER + h) * DST;
#pragma unroll
    for (int d = 0; d < DST; ++d) {
        f16x2 sp;
        sp.x = (f16)st[d];
        sp.y = (f16)__expf(A[d] * dtsum);
        a.SPbuf[base + d] = sp;
    }
}

// ---------------------------------------------------------------------------
// L7: scan pass2 over chunk aggregates (128 blocks)
// ---------------------------------------------------------------------------
__global__ __launch_bounds__(256) void k_pass2(Args a)
{
    int i = blockIdx.x * 256 + threadIdx.x;   // over INTER*DST = 32768
    float carry = 0.0f;
#pragma unroll 8
    for (int c = 0; c < NC; ++c) {
        size_t idx = (size_t)c * (INTER * DST) + i;
        f16x2 sp = a.SPbuf[idx];
        a.Cin[idx] = (f16)carry;
        carry = fmaf((float)sp.y, carry, (float)sp.x);
    }
}

// ---------------------------------------------------------------------------
// L8: scan pass3 + fused epilogue -> yh (512 blocks)
// ---------------------------------------------------------------------------
__global__ __launch_bounds__(256) void k_pass3(Args a)
{
    __shared__ float Bsc[LCH * DST];
    __shared__ float Csc[LCH * DST];
    const int v = blockIdx.x, tid = threadIdx.x;
    const int hblk = v >> 6, c = v & 63;
    const int h = hblk * 256 + tid;
    const int s0 = c * LCH;
    for (int j = tid; j < LCH * DST; j += 256) {
        int r = j >> 4, dd = j & 15;
        Bsc[r * DST + dd] = a.ssm_p[(size_t)(s0 + r) * NP + DTR + dd];
        Csc[r * DST + dd] = a.ssm_p[(size_t)(s0 + r) * NP + DTR + DST + dd];
    }
    __syncthreads();

    float A[DST], st[DST];
    size_t base = ((size_t)c * INTER + h) * DST;
#pragma unroll
    for (int d = 0; d < DST; ++d) {
        A[d] = -__expf(a.A_log[(size_t)h * DST + d]);
        st[d] = (float)a.Cin[base + d];
    }
    const float Dvv = a.Dv[h];

#pragma unroll 2
    for (int r = 0; r < LCH; ++r) {
        float dtv = (float)a.dtbh[(size_t)(s0 + r) * INTER + h];
        float hv  = (float)a.hh[(size_t)(s0 + r) * INTER + h];
        float g   = (float)a.projh[(size_t)(s0 + r) * 4096 + INTER + h];
        float dh = dtv * hv;
        float y = 0.0f;
#pragma unroll
        for (int d = 0; d < DST; ++d) {
            float da = __expf(dtv * A[d]);
            st[d] = fmaf(da, st[d], dh * Bsc[r * DST + d]);
            y = fmaf(st[d], Csc[r * DST + d], y);
        }
        y = fmaf(hv, Dvv, y);
        a.yh[(size_t)(s0 + r) * INTER + h] = (f16)(y * siluf_(g));
    }
}

// ---------------------------------------------------------------------------
// L9: out = y @ W_out (256 blocks)
// ---------------------------------------------------------------------------
__global__ __launch_bounds__(256) void k_gemm2(Args a)
{
    __shared__ __align__(16) f16 As[64 * 64];
    __shared__ __align__(16) f16 Bs[128 * 64];
    gemm_tile<64, 128, INTER, float>(a.yh, a.W_out_t, a.out, HID,
                                     (int)blockIdx.x & 7, (int)blockIdx.x >> 3,
                                     threadIdx.x, As, Bs);
}

// ---------------------------------------------------------------------------
extern "C" void kernel_launch(void* const* d_in, const int* in_sizes, int n_in,
                              void* d_out, int out_size, void* d_ws, size_t ws_size,
                              hipStream_t stream)
{
    float* ws = (float*)d_ws;
    Args a;
    a.x      = (const float*)d_in[0];
    a.W_in   = (const float*)d_in[1];
    a.conv_w = (const float*)d_in[2];
    a.conv_b = (const float*)d_in[3];
    a.W_x    = (const float*)d_in[4];
    a.W_dt   = (const float*)d_in[5];
    a.b_dt   = (const float*)d_in[6];
    a.A_log  = (const float*)d_in[7];
    a.Dv     = (const float*)d_in[8];
    a.W_out  = (const float*)d_in[9];
    a.out    = (float*)d_out;

    a.projh  = (f16*)ws;                     // SEQ x 4096 halves
    a.hh     = (f16*)(ws + 4194304);         // SEQ x INTER
    a.dtbh   = (f16*)(ws + 6291456);         // SEQ x INTER
    a.yh     = (f16*)(ws + 8388608);         // SEQ x INTER
    a.xh     = (f16*)(ws + 10485760);        // SEQ x HID
    a.W_in_t = (f16*)(ws + 11534336);        // 4096 x HID
    a.W_out_t= (f16*)(ws + 13631488);        // HID x INTER
    a.WxT    = (f16*)(ws + 14680064);        // 96 x INTER
    a.tsh    = (f16*)(ws + 14778368);        // SEQ x DTR
    a.WdtT   = (f16*)(ws + 14843904);        // INTER x DTR
    a.ssm_p  = ws + 14909440;                // SEQ x NP f32
    a.parts  = (f16*)(ws + 15106048);        // KS x SEQ x NP halves
    a.SPbuf  = (f16x2*)(ws + 16678912);      // NC x INTER x DST f16x2
    a.Cin    = (f16*)(ws + 18776064);        // NC x INTER x DST f16

    k_prep  <<<8512, 256, 0, stream>>>(a);
    k_gemm1 <<<512,  256, 0, stream>>>(a);
    k_hwxc  <<<256,  256, 0, stream>>>(a);
    k_reduce<<<96,   256, 0, stream>>>(a);
    k_dt    <<<256,  256, 0, stream>>>(a);
    k_pass1 <<<512,  256, 0, stream>>>(a);
    k_pass2 <<<128,  256, 0, stream>>>(a);
    k_pass3 <<<512,  256, 0, stream>>>(a);
    k_gemm2 <<<256,  256, 0, stream>>>(a);
}